// Round 3
// baseline (140.667 us; speedup 1.0000x reference)
//
#include <hip/hip_runtime.h>
#include <hip/hip_bf16.h>
#include <cstdint>
#include <math.h>

// Shapes: B=256, P=128, K=512, HE=1024, HF=512 (2HF=1024), D=2560, HID=64
// Outputs: embeddings (256,1,1536) then weights (256,128), fp32, flat-concat.
//
// R10: kill the 133 KB LDS keys tile (it capped attn at 1 block/CU and kept
//   it latency-bound at ~40 us since R7). Three kernels:
//   prep:   w1kt repack (8 blocks) + proj GEMV (64 blocks, 8 waves x 256-d
//           chunks, depth-4 register prefetch) -> ~4 us.
//   scores: grid 512 x 256 thr, ZERO LDS, no barrier. Wave = 16 p-rows x
//           full K, MFMA A direct-from-global. 2 blocks/CU -> 8 waves/CU,
//           >=16 KB loads in flight/CU (Little's law needs ~9 KB) -> keys
//           64 MB HBM-BW-bound ~11 us.
//   ctx:    grid 256 x 512 thr. Softmax + context re-reading keys from L3
//           (scores just streamed them; 64 MB << 256 MB L3), thread-per-col,
//           16-deep reg prefetch -> ~3 us. f32 keys (better numerics).
// Ledger (attn-path µs): R7 fused+LDS 42 | R8 direct-global 1blk/CU ~40 |
//   R9 prep GEMV latency-bound ~13. Kernel budget this round: ~20 us.
// Fixed harness overhead: ~82 µs of 256 MiB workspace-poison fills per
//   iteration (2 x 41 µs fillBufferAligned) — not addressable from here.

typedef __bf16 bf16;
typedef __attribute__((ext_vector_type(8))) __bf16 bf16x8;
typedef __attribute__((ext_vector_type(4))) float f32x4;

#define NB 256
#define NP 128
#define NK 512

// ---------------- prep: w1kt repack + fp32 proj GEMV ----------------
// blocks 0..7  : w1kt[h][k] = bf16(W1[k*64+h]), k-rows [64j, 64j+64)
// blocks 8..71 : proj[b][h] = sum_d qf[b][d]*W1[512+d][h], 4 batches/block,
//                8 waves, wave w covers d-chunk [256w, 256w+256)
__global__ __launch_bounds__(512) void prep_kernel(
    const float* __restrict__ W1, const float* __restrict__ query,
    const float* __restrict__ frame, bf16* __restrict__ w1kt,
    float* __restrict__ proj)
{
    __shared__ float s[64][65];       // repack staging (16.6 KB)
    __shared__ float sq[4][2048];     // qf for 4 batches (32 KB)
    __shared__ float red[8][4][64];   // cross-wave reduce (8 KB)
    const int blk = blockIdx.x;
    const int t = threadIdx.x;
    if (blk < 8) {
        const int k0 = blk * 64;
#pragma unroll
        for (int i = 0; i < 8; i++) {
            const int idx = t + 512 * i;
            const int k = idx >> 6, h = idx & 63;
            s[k][h] = W1[(size_t)(k0 + k) * 64 + h];
        }
        __syncthreads();
#pragma unroll
        for (int i = 0; i < 8; i++) {
            const int idx = t + 512 * i;
            const int h = idx >> 6, kk = idx & 63;
            w1kt[(size_t)h * 512 + k0 + kk] = (bf16)s[kk][h];
        }
    } else {
        const int b0 = (blk - 8) * 4;
        // stage qf = concat(query[b], frame[b]): 4 float4 / thread, coalesced
#pragma unroll
        for (int i = 0; i < 4; i++) {
            const int flat = (t + 512 * i) * 4;   // float index 0..8191
            const int bl = flat >> 11;            // local batch 0..3
            const int d  = flat & 2047;
            const float* src = (d < 1024)
                ? (query + (size_t)(b0 + bl) * 1024 + d)
                : (frame + (size_t)(b0 + bl) * 1024 + (d - 1024));
            *(float4*)&sq[bl][d] = *(const float4*)src;
        }
        __syncthreads();

        const int w = t >> 6;        // wave's d-chunk: [256w, 256w+256)
        const int h = t & 63;
        const float* w1c = W1 + (size_t)(512 + w * 256) * 64 + h;  // coalesced over h
        float wreg[4][16];           // depth-4 prefetch: 48 loads in flight
#pragma unroll
        for (int bu = 0; bu < 3; bu++)
#pragma unroll
            for (int u = 0; u < 16; u++)
                wreg[bu][u] = w1c[(size_t)(bu * 16 + u) * 64];

        float acc[4] = {0.f, 0.f, 0.f, 0.f};
#pragma unroll
        for (int rr = 0; rr < 16; rr++) {     // full unroll -> static indices
            const int cur = rr & 3;
            if (rr < 13) {
#pragma unroll
                for (int u = 0; u < 16; u++)
                    wreg[(rr + 3) & 3][u] = w1c[(size_t)((rr + 3) * 16 + u) * 64];
            }
#pragma unroll
            for (int u4 = 0; u4 < 4; u4++) {
                float4 qv[4];                 // LDS broadcast reads
#pragma unroll
                for (int j = 0; j < 4; j++)
                    qv[j] = *(const float4*)&sq[j][w * 256 + rr * 16 + u4 * 4];
#pragma unroll
                for (int uu = 0; uu < 4; uu++) {
                    const float wv = wreg[cur][u4 * 4 + uu];
                    acc[0] += (&qv[0].x)[uu] * wv;
                    acc[1] += (&qv[1].x)[uu] * wv;
                    acc[2] += (&qv[2].x)[uu] * wv;
                    acc[3] += (&qv[3].x)[uu] * wv;
                }
            }
        }
#pragma unroll
        for (int j = 0; j < 4; j++) red[w][j][h] = acc[j];
        __syncthreads();
        if (t < 256) {
            const int j2 = t >> 6, hh = t & 63;
            float sum = 0.f;
#pragma unroll
            for (int ww = 0; ww < 8; ww++) sum += red[ww][j2][hh];
            proj[(size_t)(b0 + j2) * 64 + hh] = sum;
        }
    }
}

// ---------------- scores: grid 512, 256 thr, zero LDS ----------------
// block (b = blk>>1, ph = blk&1); wave w owns rows p0 = ph*64 + w*16,
// full K=512. sws[b][p] = relu(keys@W1k + proj) @ W2.
__global__ __launch_bounds__(256, 2) void scores_kernel(
    const float* __restrict__ keys, const float* __restrict__ W2,
    const bf16* __restrict__ w1kt, const float* __restrict__ proj,
    float* __restrict__ sws)
{
    const int blk = blockIdx.x;
    const int b = blk >> 1;
    const int ph = blk & 1;
    const int t = threadIdx.x;
    const int w = t >> 6;
    const int lane = t & 63;
    const int m = lane & 15;
    const int q = lane >> 4;
    const int p0 = ph * 64 + w * 16;

    float pv[4], wv[4];
#pragma unroll
    for (int nt = 0; nt < 4; nt++) {
        pv[nt] = proj[b * 64 + nt * 16 + m];
        wv[nt] = W2[nt * 16 + m];
    }

    const float* arow = keys + (size_t)b * (NP * NK) + (size_t)(p0 + m) * NK + q * 8;
    const bf16* bb = w1kt + m * 512 + q * 8;          // + nt*8192 + kk*32

    f32x4 acc[4];
#pragma unroll
    for (int nt = 0; nt < 4; nt++) acc[nt] = (f32x4){0.f, 0.f, 0.f, 0.f};

    float4 Aa[2], Ab[2];
    bf16x8 Bp[2][4];
    Aa[0] = *(const float4*)(arow);
    Ab[0] = *(const float4*)(arow + 4);
#pragma unroll
    for (int nt = 0; nt < 4; nt++) Bp[0][nt] = *(const bf16x8*)(bb + nt * 8192);

#pragma unroll
    for (int kk = 0; kk < 16; kk++) {
        const int cur = kk & 1;
        if (kk < 15) {
            Aa[cur ^ 1] = *(const float4*)(arow + (kk + 1) * 32);
            Ab[cur ^ 1] = *(const float4*)(arow + (kk + 1) * 32 + 4);
#pragma unroll
            for (int nt = 0; nt < 4; nt++)
                Bp[cur ^ 1][nt] = *(const bf16x8*)(bb + nt * 8192 + (kk + 1) * 32);
        }
        bf16x8 Af;
        Af[0] = (bf16)Aa[cur].x; Af[1] = (bf16)Aa[cur].y;
        Af[2] = (bf16)Aa[cur].z; Af[3] = (bf16)Aa[cur].w;
        Af[4] = (bf16)Ab[cur].x; Af[5] = (bf16)Ab[cur].y;
        Af[6] = (bf16)Ab[cur].z; Af[7] = (bf16)Ab[cur].w;
#pragma unroll
        for (int nt = 0; nt < 4; nt++)
            acc[nt] = __builtin_amdgcn_mfma_f32_16x16x32_bf16(Af, Bp[cur][nt], acc[nt], 0, 0, 0);
    }

    // fold 64 h-columns: relu(+proj) * w2, reduce over the 16 h-lanes
    float pr[4] = {0.f, 0.f, 0.f, 0.f};
#pragma unroll
    for (int nt = 0; nt < 4; nt++)
#pragma unroll
        for (int r = 0; r < 4; r++)
            pr[r] += fmaxf(acc[nt][r] + pv[nt], 0.f) * wv[nt];

#pragma unroll
    for (int off = 1; off < 16; off <<= 1)
#pragma unroll
        for (int r = 0; r < 4; r++)
            pr[r] += __shfl_xor(pr[r], off);

    if (m == 0) {
#pragma unroll
        for (int r = 0; r < 4; r++)
            sws[(size_t)b * 128 + p0 + q * 4 + r] = pr[r];
    }
}

// ---------------- ctx: softmax + context + passthrough ----------------
// grid 256, 512 thr. keys re-read is L3-hot (scores just streamed it).
__global__ __launch_bounds__(512, 2) void ctx_kernel(
    const float* __restrict__ keys, const float* __restrict__ frame,
    const int* __restrict__ mask, const float* __restrict__ sws,
    float* __restrict__ out)
{
    __shared__ float wts[128];
    const int b = blockIdx.x;
    const int t = threadIdx.x;

    if (t < 64) {
        const int pa = t, pb = t + 64;
        float s0 = (mask[b * 128 + pa] == 0) ? -INFINITY : sws[(size_t)b * 128 + pa];
        float s1 = (mask[b * 128 + pb] == 0) ? -INFINITY : sws[(size_t)b * 128 + pb];
        float mx = fmaxf(s0, s1);
#pragma unroll
        for (int off = 32; off; off >>= 1) mx = fmaxf(mx, __shfl_xor(mx, off));
        float e0 = __expf(s0 - mx), e1 = __expf(s1 - mx);
        float sum = e0 + e1;
#pragma unroll
        for (int off = 32; off; off >>= 1) sum += __shfl_xor(sum, off);
        const float inv = 1.0f / sum;
        e0 *= inv; e1 *= inv;
        wts[pa] = e0; wts[pb] = e1;
        float* wout = out + (size_t)NB * 1536;
        wout[b * 128 + pa] = e0;
        wout[b * 128 + pb] = e1;
    }
    __syncthreads();

    // context: thread t owns column t; 16-deep double-buffered prefetch
    const float* kc = keys + (size_t)b * (NP * NK) + t;
    float kreg[2][16];
#pragma unroll
    for (int i = 0; i < 16; i++) kreg[0][i] = kc[(size_t)i * NK];
    float acc = 0.f;
#pragma unroll
    for (int c8 = 0; c8 < 8; c8++) {      // full unroll -> static indices
        const int cur = c8 & 1;
        if (c8 < 7) {
#pragma unroll
            for (int i = 0; i < 16; i++)
                kreg[cur ^ 1][i] = kc[(size_t)((c8 + 1) * 16 + i) * NK];
        }
#pragma unroll
        for (int i = 0; i < 16; i++)
            acc += wts[c8 * 16 + i] * kreg[cur][i];
    }
    out[(size_t)b * 1536 + t] = acc;

    // frame passthrough: embeddings[:, 512:1536] = frameLSTM_h
    if (t < 256) {
        const float4 fv = *(const float4*)(frame + (size_t)b * 1024 + t * 4);
        *(float4*)(out + (size_t)b * 1536 + 512 + t * 4) = fv;
    }
}

extern "C" void kernel_launch(void* const* d_in, const int* in_sizes, int n_in,
                              void* d_out, int out_size, void* d_ws, size_t ws_size,
                              hipStream_t stream) {
    const float* query = (const float*)d_in[0];
    const float* keys  = (const float*)d_in[1];
    const float* frame = (const float*)d_in[2];
    const int*   mask  = (const int*)d_in[3];
    const float* W1    = (const float*)d_in[4];
    const float* W2    = (const float*)d_in[5];
    float* out = (float*)d_out;

    // ws: [0,64K) w1kt bf16 [64][512]; [64K,128K) proj f32 [256][64];
    //     [128K,256K) sws f32 [256][128]
    bf16* w1kt  = (bf16*)d_ws;
    float* proj = (float*)((char*)d_ws + (64 << 10));
    float* sws  = (float*)((char*)d_ws + (128 << 10));

    prep_kernel<<<72, 512, 0, stream>>>(W1, query, frame, w1kt, proj);
    scores_kernel<<<512, 256, 0, stream>>>(keys, W2, w1kt, proj, sws);
    ctx_kernel<<<256, 512, 0, stream>>>(keys, frame, mask, sws, out);
}

// Round 4
// 130.611 us; speedup vs baseline: 1.0770x; 1.0770x over previous
//
#include <hip/hip_runtime.h>
#include <hip/hip_bf16.h>
#include <cstdint>
#include <math.h>

// Shapes: B=256, P=128, K=512, HE=1024, HF=512 (2HF=1024), D=2560, HID=64
// Outputs: embeddings (256,1,1536) then weights (256,128), fp32, flat-concat.
//
// R11: fix the scores vmcnt-queue pollution (the R7 ledger lesson,
//   re-violated in R8/R10): A-loads (HBM) and B-loads (L2) shared the one
//   in-order vmcnt queue, collapsing the A-prefetch to depth-1 -> ~900 cy
//   exposed per kk iteration -> scores ~30 us. Now: w1kt staged to LDS once
//   per block (64 KB, XOR-swizzled o^((row&7)<<4) so the 16-lane x 1024B
//   ds_read_b128 is 2-way/free), B rides lgkmcnt; in-loop vmcnt queue is
//   A-ONLY with depth-3-ahead prefetch. In-flight/CU = 8 waves x 6 loads x
//   2 KB = 48 KB >> 9.2 KB Little's-law need -> keys 64 MB HBM-BW-bound.
//   Bonus: B fabric traffic 128 MB -> 32 MB.
// Ledger (attn-path µs): R7 fused+LDS 42 | R8 direct-global 1blk/CU ~40 |
//   R10 split 3-kernel, kernels+gaps 59 (scores ~30: vmcnt pollution).
// Fixed harness overhead: ~82 µs of 256 MiB workspace-poison fills per
//   iteration (2 x ~41 µs fillBufferAligned) — not addressable from here.

typedef __bf16 bf16;
typedef __attribute__((ext_vector_type(8))) __bf16 bf16x8;
typedef __attribute__((ext_vector_type(4))) float f32x4;

#define NB 256
#define NP 128
#define NK 512

// ---------------- prep: w1kt repack + fp32 proj GEMV ----------------
// blocks 0..7  : w1kt[h][k] = bf16(W1[k*64+h]), k-rows [64j, 64j+64)
// blocks 8..71 : proj[b][h] = sum_d qf[b][d]*W1[512+d][h], 4 batches/block,
//                8 waves, wave w covers d-chunk [256w, 256w+256)
__global__ __launch_bounds__(512) void prep_kernel(
    const float* __restrict__ W1, const float* __restrict__ query,
    const float* __restrict__ frame, bf16* __restrict__ w1kt,
    float* __restrict__ proj)
{
    __shared__ float s[64][65];       // repack staging (16.6 KB)
    __shared__ float sq[4][2048];     // qf for 4 batches (32 KB)
    __shared__ float red[8][4][64];   // cross-wave reduce (8 KB)
    const int blk = blockIdx.x;
    const int t = threadIdx.x;
    if (blk < 8) {
        const int k0 = blk * 64;
#pragma unroll
        for (int i = 0; i < 8; i++) {
            const int idx = t + 512 * i;
            const int k = idx >> 6, h = idx & 63;
            s[k][h] = W1[(size_t)(k0 + k) * 64 + h];
        }
        __syncthreads();
#pragma unroll
        for (int i = 0; i < 8; i++) {
            const int idx = t + 512 * i;
            const int h = idx >> 6, kk = idx & 63;
            w1kt[(size_t)h * 512 + k0 + kk] = (bf16)s[kk][h];
        }
    } else {
        const int b0 = (blk - 8) * 4;
        // stage qf = concat(query[b], frame[b]): 4 float4 / thread, coalesced
#pragma unroll
        for (int i = 0; i < 4; i++) {
            const int flat = (t + 512 * i) * 4;   // float index 0..8191
            const int bl = flat >> 11;            // local batch 0..3
            const int d  = flat & 2047;
            const float* src = (d < 1024)
                ? (query + (size_t)(b0 + bl) * 1024 + d)
                : (frame + (size_t)(b0 + bl) * 1024 + (d - 1024));
            *(float4*)&sq[bl][d] = *(const float4*)src;
        }
        __syncthreads();

        const int w = t >> 6;        // wave's d-chunk: [256w, 256w+256)
        const int h = t & 63;
        const float* w1c = W1 + (size_t)(512 + w * 256) * 64 + h;  // coalesced over h
        float wreg[4][16];           // depth-4 prefetch: 48 loads in flight
#pragma unroll
        for (int bu = 0; bu < 3; bu++)
#pragma unroll
            for (int u = 0; u < 16; u++)
                wreg[bu][u] = w1c[(size_t)(bu * 16 + u) * 64];

        float acc[4] = {0.f, 0.f, 0.f, 0.f};
#pragma unroll
        for (int rr = 0; rr < 16; rr++) {     // full unroll -> static indices
            const int cur = rr & 3;
            if (rr < 13) {
#pragma unroll
                for (int u = 0; u < 16; u++)
                    wreg[(rr + 3) & 3][u] = w1c[(size_t)((rr + 3) * 16 + u) * 64];
            }
#pragma unroll
            for (int u4 = 0; u4 < 4; u4++) {
                float4 qv[4];                 // LDS broadcast reads
#pragma unroll
                for (int j = 0; j < 4; j++)
                    qv[j] = *(const float4*)&sq[j][w * 256 + rr * 16 + u4 * 4];
#pragma unroll
                for (int uu = 0; uu < 4; uu++) {
                    const float wv = wreg[cur][u4 * 4 + uu];
                    acc[0] += (&qv[0].x)[uu] * wv;
                    acc[1] += (&qv[1].x)[uu] * wv;
                    acc[2] += (&qv[2].x)[uu] * wv;
                    acc[3] += (&qv[3].x)[uu] * wv;
                }
            }
        }
#pragma unroll
        for (int j = 0; j < 4; j++) red[w][j][h] = acc[j];
        __syncthreads();
        if (t < 256) {
            const int j2 = t >> 6, hh = t & 63;
            float sum = 0.f;
#pragma unroll
            for (int ww = 0; ww < 8; ww++) sum += red[ww][j2][hh];
            proj[(size_t)(b0 + j2) * 64 + hh] = sum;
        }
    }
}

// ---------------- scores: grid 512, 256 thr, w1kt in LDS ----------------
// block (b = blk>>1, ph = blk&1); wave w owns rows p0 = ph*64 + w*16,
// full K=512. sws[b][p] = relu(keys@W1k + proj) @ W2.
// LDS: 64 KB swizzled w1kt copy; lds[o ^ ((row&7)<<4)] = w1kt_bytes[o].
__global__ __launch_bounds__(256) void scores_kernel(
    const float* __restrict__ keys, const float* __restrict__ W2,
    const bf16* __restrict__ w1kt, const float* __restrict__ proj,
    float* __restrict__ sws)
{
    extern __shared__ char sB[];              // 64 KB
    const int blk = blockIdx.x;
    const int b = blk >> 1;
    const int ph = blk & 1;
    const int t = threadIdx.x;
    const int w = t >> 6;
    const int lane = t & 63;
    const int m = lane & 15;
    const int q = lane >> 4;
    const int p0 = ph * 64 + w * 16;
    const int xorv = (m & 7) << 4;            // read-side swizzle (bits 4-6)

    const float* arow = keys + (size_t)b * (NP * NK) + (size_t)(p0 + m) * NK + q * 8;

    // issue the first A prefetches before the B copy (they ride ahead in HBM)
    float4 Aa[4], Ab[4];
#pragma unroll
    for (int i = 0; i < 3; i++) {
        Aa[i] = *(const float4*)(arow + i * 32);
        Ab[i] = *(const float4*)(arow + i * 32 + 4);
    }

    // stage w1kt -> LDS, swizzled (write side of the same involution)
    {
        const char* wsrc = (const char*)w1kt;
#pragma unroll
        for (int i = 0; i < 16; i++) {
            const int o = t * 256 + i * 16;
            const int row = o >> 10;          // 1024 B per h-row
            *(bf16x8*)(sB + (o ^ ((row & 7) << 4))) = *(const bf16x8*)(wsrc + o);
        }
    }

    float pv[4], wv[4];
#pragma unroll
    for (int nt = 0; nt < 4; nt++) {
        pv[nt] = proj[b * 64 + nt * 16 + m];
        wv[nt] = W2[nt * 16 + m];
    }
    __syncthreads();   // drains vmcnt once; steady-state loop has no barrier

    f32x4 acc[4];
#pragma unroll
    for (int nt = 0; nt < 4; nt++) acc[nt] = (f32x4){0.f, 0.f, 0.f, 0.f};

    // B fragment addr: nt*16384 + m*1024 + ((kk*64 | q*16) ^ xorv)
    bf16x8 Bp[2][4];
#pragma unroll
    for (int nt = 0; nt < 4; nt++)
        Bp[0][nt] = *(const bf16x8*)(sB + nt * 16384 + m * 1024 + ((q * 16) ^ xorv));

#pragma unroll
    for (int kk = 0; kk < 16; kk++) {         // full unroll -> static indices
        const int cur = kk & 3;
        const int bc = kk & 1;
        if (kk < 13) {                        // A: depth-3-ahead, vmcnt-only queue
            Aa[(kk + 3) & 3] = *(const float4*)(arow + (kk + 3) * 32);
            Ab[(kk + 3) & 3] = *(const float4*)(arow + (kk + 3) * 32 + 4);
        }
        if (kk < 15) {                        // B: depth-1-ahead via lgkmcnt
#pragma unroll
            for (int nt = 0; nt < 4; nt++)
                Bp[bc ^ 1][nt] = *(const bf16x8*)(sB + nt * 16384 + m * 1024
                                  + ((((kk + 1) * 64) | (q * 16)) ^ xorv));
        }
        bf16x8 Af;
        Af[0] = (bf16)Aa[cur].x; Af[1] = (bf16)Aa[cur].y;
        Af[2] = (bf16)Aa[cur].z; Af[3] = (bf16)Aa[cur].w;
        Af[4] = (bf16)Ab[cur].x; Af[5] = (bf16)Ab[cur].y;
        Af[6] = (bf16)Ab[cur].z; Af[7] = (bf16)Ab[cur].w;
#pragma unroll
        for (int nt = 0; nt < 4; nt++)
            acc[nt] = __builtin_amdgcn_mfma_f32_16x16x32_bf16(Af, Bp[bc][nt], acc[nt], 0, 0, 0);
    }

    // fold 64 h-columns: relu(+proj) * w2, reduce over the 16 h-lanes
    float pr[4] = {0.f, 0.f, 0.f, 0.f};
#pragma unroll
    for (int nt = 0; nt < 4; nt++)
#pragma unroll
        for (int r = 0; r < 4; r++)
            pr[r] += fmaxf(acc[nt][r] + pv[nt], 0.f) * wv[nt];

#pragma unroll
    for (int off = 1; off < 16; off <<= 1)
#pragma unroll
        for (int r = 0; r < 4; r++)
            pr[r] += __shfl_xor(pr[r], off);

    if (m == 0) {
#pragma unroll
        for (int r = 0; r < 4; r++)
            sws[(size_t)b * 128 + p0 + q * 4 + r] = pr[r];
    }
}

// ---------------- ctx: softmax + context + passthrough ----------------
// grid 256, 512 thr. keys re-read is L3-hot (scores just streamed it).
__global__ __launch_bounds__(512, 2) void ctx_kernel(
    const float* __restrict__ keys, const float* __restrict__ frame,
    const int* __restrict__ mask, const float* __restrict__ sws,
    float* __restrict__ out)
{
    __shared__ float wts[128];
    const int b = blockIdx.x;
    const int t = threadIdx.x;

    if (t < 64) {
        const int pa = t, pb = t + 64;
        float s0 = (mask[b * 128 + pa] == 0) ? -INFINITY : sws[(size_t)b * 128 + pa];
        float s1 = (mask[b * 128 + pb] == 0) ? -INFINITY : sws[(size_t)b * 128 + pb];
        float mx = fmaxf(s0, s1);
#pragma unroll
        for (int off = 32; off; off >>= 1) mx = fmaxf(mx, __shfl_xor(mx, off));
        float e0 = __expf(s0 - mx), e1 = __expf(s1 - mx);
        float sum = e0 + e1;
#pragma unroll
        for (int off = 32; off; off >>= 1) sum += __shfl_xor(sum, off);
        const float inv = 1.0f / sum;
        e0 *= inv; e1 *= inv;
        wts[pa] = e0; wts[pb] = e1;
        float* wout = out + (size_t)NB * 1536;
        wout[b * 128 + pa] = e0;
        wout[b * 128 + pb] = e1;
    }
    __syncthreads();

    // context: thread t owns column t; 16-deep double-buffered prefetch
    const float* kc = keys + (size_t)b * (NP * NK) + t;
    float kreg[2][16];
#pragma unroll
    for (int i = 0; i < 16; i++) kreg[0][i] = kc[(size_t)i * NK];
    float acc = 0.f;
#pragma unroll
    for (int c8 = 0; c8 < 8; c8++) {      // full unroll -> static indices
        const int cur = c8 & 1;
        if (c8 < 7) {
#pragma unroll
            for (int i = 0; i < 16; i++)
                kreg[cur ^ 1][i] = kc[(size_t)((c8 + 1) * 16 + i) * NK];
        }
#pragma unroll
        for (int i = 0; i < 16; i++)
            acc += wts[c8 * 16 + i] * kreg[cur][i];
    }
    out[(size_t)b * 1536 + t] = acc;

    // frame passthrough: embeddings[:, 512:1536] = frameLSTM_h
    if (t < 256) {
        const float4 fv = *(const float4*)(frame + (size_t)b * 1024 + t * 4);
        *(float4*)(out + (size_t)b * 1536 + 512 + t * 4) = fv;
    }
}

extern "C" void kernel_launch(void* const* d_in, const int* in_sizes, int n_in,
                              void* d_out, int out_size, void* d_ws, size_t ws_size,
                              hipStream_t stream) {
    const float* query = (const float*)d_in[0];
    const float* keys  = (const float*)d_in[1];
    const float* frame = (const float*)d_in[2];
    const int*   mask  = (const int*)d_in[3];
    const float* W1    = (const float*)d_in[4];
    const float* W2    = (const float*)d_in[5];
    float* out = (float*)d_out;

    // ws: [0,64K) w1kt bf16 [64][512]; [64K,128K) proj f32 [256][64];
    //     [128K,256K) sws f32 [256][128]
    bf16* w1kt  = (bf16*)d_ws;
    float* proj = (float*)((char*)d_ws + (64 << 10));
    float* sws  = (float*)((char*)d_ws + (128 << 10));

    hipFuncSetAttribute((const void*)scores_kernel,
                        hipFuncAttributeMaxDynamicSharedMemorySize, 65536);

    prep_kernel<<<72, 512, 0, stream>>>(W1, query, frame, w1kt, proj);
    scores_kernel<<<512, 256, 65536, stream>>>(keys, W2, w1kt, proj, sws);
    ctx_kernel<<<256, 512, 0, stream>>>(keys, frame, mask, sws, out);
}

// Round 5
// 123.594 us; speedup vs baseline: 1.1381x; 1.0568x over previous
//
#include <hip/hip_runtime.h>
#include <hip/hip_bf16.h>
#include <cstdint>
#include <math.h>

// Shapes: B=256, P=128, K=512, HE=1024, HF=512 (2HF=1024), D=2560, HID=64
// Outputs: embeddings (256,1,1536) then weights (256,128), fp32, flat-concat.
//
// R12: fuse scores+ctx (R11's ctx was the least-defended cost: 64 MB L3
//   re-read, L2-evicted keys, extra launch + sws round-trip). One block per
//   batch: 8 waves x 16 p-rows, w1kt staged to LDS swizzled (B on lgkmcnt;
//   in-loop vmcnt queue is A-ONLY), A-prefetch distance-6 ring-of-8
//   (12 loads in flight -> 96 KB/CU >> 9.2 KB Little's-law need; issue-to-
//   consume ~550 cy covers most of HBM latency per-wave). Tail: in-block
//   softmax + context re-reading keys[b] from L2/L3 (just streamed by this
//   block). prep unchanged.
// Ledger (kernels+gaps µs): R7 45 | R9 55.6 | R10 59 (vmcnt pollution) |
//   R11 48.8 (LDS-B fix, -10). Floors: scores ~11 (keys 64 MB HBM), ctx ~3,
//   prep ~4.
// Fixed harness overhead: ~82 µs of 256 MiB workspace-poison fills per
//   iteration (2 x ~41 µs fillBufferAligned) — not addressable from here.

typedef __bf16 bf16;
typedef __attribute__((ext_vector_type(8))) __bf16 bf16x8;
typedef __attribute__((ext_vector_type(4))) float f32x4;

#define NB 256
#define NP 128
#define NK 512
#define SMEM_BYTES (65536 + 256 * 4)   // w1kt swizzled + scores[128] + wts[128]

// ---------------- prep: w1kt repack + fp32 proj GEMV ----------------
// blocks 0..7  : w1kt[h][k] = bf16(W1[k*64+h]), k-rows [64j, 64j+64)
// blocks 8..71 : proj[b][h] = sum_d qf[b][d]*W1[512+d][h], 4 batches/block,
//                8 waves, wave w covers d-chunk [256w, 256w+256)
__global__ __launch_bounds__(512) void prep_kernel(
    const float* __restrict__ W1, const float* __restrict__ query,
    const float* __restrict__ frame, bf16* __restrict__ w1kt,
    float* __restrict__ proj)
{
    __shared__ float s[64][65];       // repack staging (16.6 KB)
    __shared__ float sq[4][2048];     // qf for 4 batches (32 KB)
    __shared__ float red[8][4][64];   // cross-wave reduce (8 KB)
    const int blk = blockIdx.x;
    const int t = threadIdx.x;
    if (blk < 8) {
        const int k0 = blk * 64;
#pragma unroll
        for (int i = 0; i < 8; i++) {
            const int idx = t + 512 * i;
            const int k = idx >> 6, h = idx & 63;
            s[k][h] = W1[(size_t)(k0 + k) * 64 + h];
        }
        __syncthreads();
#pragma unroll
        for (int i = 0; i < 8; i++) {
            const int idx = t + 512 * i;
            const int h = idx >> 6, kk = idx & 63;
            w1kt[(size_t)h * 512 + k0 + kk] = (bf16)s[kk][h];
        }
    } else {
        const int b0 = (blk - 8) * 4;
        // stage qf = concat(query[b], frame[b]): 4 float4 / thread, coalesced
#pragma unroll
        for (int i = 0; i < 4; i++) {
            const int flat = (t + 512 * i) * 4;   // float index 0..8191
            const int bl = flat >> 11;            // local batch 0..3
            const int d  = flat & 2047;
            const float* src = (d < 1024)
                ? (query + (size_t)(b0 + bl) * 1024 + d)
                : (frame + (size_t)(b0 + bl) * 1024 + (d - 1024));
            *(float4*)&sq[bl][d] = *(const float4*)src;
        }
        __syncthreads();

        const int w = t >> 6;        // wave's d-chunk: [256w, 256w+256)
        const int h = t & 63;
        const float* w1c = W1 + (size_t)(512 + w * 256) * 64 + h;  // coalesced over h
        float wreg[4][16];           // depth-4 prefetch: 48 loads in flight
#pragma unroll
        for (int bu = 0; bu < 3; bu++)
#pragma unroll
            for (int u = 0; u < 16; u++)
                wreg[bu][u] = w1c[(size_t)(bu * 16 + u) * 64];

        float acc[4] = {0.f, 0.f, 0.f, 0.f};
#pragma unroll
        for (int rr = 0; rr < 16; rr++) {     // full unroll -> static indices
            const int cur = rr & 3;
            if (rr < 13) {
#pragma unroll
                for (int u = 0; u < 16; u++)
                    wreg[(rr + 3) & 3][u] = w1c[(size_t)((rr + 3) * 16 + u) * 64];
            }
#pragma unroll
            for (int u4 = 0; u4 < 4; u4++) {
                float4 qv[4];                 // LDS broadcast reads
#pragma unroll
                for (int j = 0; j < 4; j++)
                    qv[j] = *(const float4*)&sq[j][w * 256 + rr * 16 + u4 * 4];
#pragma unroll
                for (int uu = 0; uu < 4; uu++) {
                    const float wv = wreg[cur][u4 * 4 + uu];
                    acc[0] += (&qv[0].x)[uu] * wv;
                    acc[1] += (&qv[1].x)[uu] * wv;
                    acc[2] += (&qv[2].x)[uu] * wv;
                    acc[3] += (&qv[3].x)[uu] * wv;
                }
            }
        }
#pragma unroll
        for (int j = 0; j < 4; j++) red[w][j][h] = acc[j];
        __syncthreads();
        if (t < 256) {
            const int j2 = t >> 6, hh = t & 63;
            float sum = 0.f;
#pragma unroll
            for (int ww = 0; ww < 8; ww++) sum += red[ww][j2][hh];
            proj[(size_t)(b0 + j2) * 64 + hh] = sum;
        }
    }
}

// ---------------- attn: fused scores+softmax+context, 1 block/batch ----------------
// 512 thr = 8 waves; wave w owns p-rows [16w, 16w+16), full K=512.
// LDS: 64 KB swizzled w1kt + scores[128] + wts[128].
__global__ __launch_bounds__(512) void attn_kernel(
    const float* __restrict__ keys, const float* __restrict__ frame,
    const int* __restrict__ mask, const float* __restrict__ W2,
    const bf16* __restrict__ w1kt, const float* __restrict__ proj,
    float* __restrict__ out)
{
    extern __shared__ char smem[];
    char* sB      = smem;                        // 64 KB swizzled w1kt
    float* scores = (float*)(smem + 65536);      // [128]
    float* wts    = scores + 128;                // [128]

    const int b = blockIdx.x;
    const int t = threadIdx.x;
    const int w = t >> 6;
    const int lane = t & 63;
    const int m = lane & 15;
    const int q = lane >> 4;
    const int p0 = w * 16;
    const int xorv = (m & 7) << 4;               // read-side swizzle (bits 4-6)

    const float* arow = keys + (size_t)b * (NP * NK) + (size_t)(p0 + m) * NK + q * 8;

    // A prologue: distance-6 prefetch (12 loads) issued before staging
    float4 Aa[8], Ab[8];
#pragma unroll
    for (int i = 0; i < 6; i++) {
        Aa[i] = *(const float4*)(arow + i * 32);
        Ab[i] = *(const float4*)(arow + i * 32 + 4);
    }

    // stage w1kt -> LDS, swizzled: lds[o ^ ((row&7)<<4)] = w1kt_bytes[o]
    {
        const char* wsrc = (const char*)w1kt;
#pragma unroll
        for (int i = 0; i < 8; i++) {
            const int o = i * 8192 + t * 16;
            const int row = o >> 10;             // 1024 B per h-row
            *(bf16x8*)(sB + (o ^ ((row & 7) << 4))) = *(const bf16x8*)(wsrc + o);
        }
    }

    float pv[4], wv[4];
#pragma unroll
    for (int nt = 0; nt < 4; nt++) {
        pv[nt] = proj[b * 64 + nt * 16 + m];
        wv[nt] = W2[nt * 16 + m];
    }
    __syncthreads();   // one-time full drain; steady-state loop has no barrier

    f32x4 acc[4];
#pragma unroll
    for (int nt = 0; nt < 4; nt++) acc[nt] = (f32x4){0.f, 0.f, 0.f, 0.f};

    // B fragment addr: nt*16384 + m*1024 + ((kk*64 | q*16) ^ xorv)
    bf16x8 Bp[2][4];
#pragma unroll
    for (int nt = 0; nt < 4; nt++)
        Bp[0][nt] = *(const bf16x8*)(sB + nt * 16384 + m * 1024 + ((q * 16) ^ xorv));

#pragma unroll
    for (int kk = 0; kk < 16; kk++) {            // full unroll -> static indices
        const int cur = kk & 7;
        const int bc = kk & 1;
        if (kk < 10) {                           // A: distance-6, vmcnt-only queue
            Aa[(kk + 6) & 7] = *(const float4*)(arow + (kk + 6) * 32);
            Ab[(kk + 6) & 7] = *(const float4*)(arow + (kk + 6) * 32 + 4);
        }
        if (kk < 15) {                           // B: depth-1-ahead via lgkmcnt
#pragma unroll
            for (int nt = 0; nt < 4; nt++)
                Bp[bc ^ 1][nt] = *(const bf16x8*)(sB + nt * 16384 + m * 1024
                                  + ((((kk + 1) * 64) | (q * 16)) ^ xorv));
        }
        bf16x8 Af;
        Af[0] = (bf16)Aa[cur].x; Af[1] = (bf16)Aa[cur].y;
        Af[2] = (bf16)Aa[cur].z; Af[3] = (bf16)Aa[cur].w;
        Af[4] = (bf16)Ab[cur].x; Af[5] = (bf16)Ab[cur].y;
        Af[6] = (bf16)Ab[cur].z; Af[7] = (bf16)Ab[cur].w;
#pragma unroll
        for (int nt = 0; nt < 4; nt++)
            acc[nt] = __builtin_amdgcn_mfma_f32_16x16x32_bf16(Af, Bp[bc][nt], acc[nt], 0, 0, 0);
    }

    // fold 64 h-columns: relu(+proj) * w2, reduce over the 16 h-lanes
    float pr[4] = {0.f, 0.f, 0.f, 0.f};
#pragma unroll
    for (int nt = 0; nt < 4; nt++)
#pragma unroll
        for (int r = 0; r < 4; r++)
            pr[r] += fmaxf(acc[nt][r] + pv[nt], 0.f) * wv[nt];

#pragma unroll
    for (int off = 1; off < 16; off <<= 1)
#pragma unroll
        for (int r = 0; r < 4; r++)
            pr[r] += __shfl_xor(pr[r], off);

    if (m == 0) {
#pragma unroll
        for (int r = 0; r < 4; r++) scores[p0 + q * 4 + r] = pr[r];
    }
    __syncthreads();

    // ---- masked softmax over 128 scores (first 64 lanes), write weights ----
    if (t < 64) {
        const int pa = t, pb = t + 64;
        float s0 = (mask[b * 128 + pa] == 0) ? -INFINITY : scores[pa];
        float s1 = (mask[b * 128 + pb] == 0) ? -INFINITY : scores[pb];
        float mx = fmaxf(s0, s1);
#pragma unroll
        for (int off = 32; off; off >>= 1) mx = fmaxf(mx, __shfl_xor(mx, off));
        float e0 = __expf(s0 - mx), e1 = __expf(s1 - mx);
        float sum = e0 + e1;
#pragma unroll
        for (int off = 32; off; off >>= 1) sum += __shfl_xor(sum, off);
        const float inv = 1.0f / sum;
        e0 *= inv; e1 *= inv;
        wts[pa] = e0; wts[pb] = e1;
        float* wout = out + (size_t)NB * 1536;
        wout[b * 128 + pa] = e0;
        wout[b * 128 + pb] = e1;
    }
    __syncthreads();

    // ---- context: thread t owns col t; keys[b] is L2/L3-hot (just streamed) ----
    {
        const float* kc = keys + (size_t)b * (NP * NK) + t;
        float kreg[2][16];
#pragma unroll
        for (int i = 0; i < 16; i++) kreg[0][i] = kc[(size_t)i * NK];
        float acc2 = 0.f;
#pragma unroll
        for (int c8 = 0; c8 < 8; c8++) {         // full unroll -> static indices
            const int cu2 = c8 & 1;
            if (c8 < 7) {
#pragma unroll
                for (int i = 0; i < 16; i++)
                    kreg[cu2 ^ 1][i] = kc[(size_t)((c8 + 1) * 16 + i) * NK];
            }
#pragma unroll
            for (int i = 0; i < 16; i++)
                acc2 += wts[c8 * 16 + i] * kreg[cu2][i];
        }
        out[(size_t)b * 1536 + t] = acc2;
    }
    // ---- frame passthrough: embeddings[:, 512:1536] = frameLSTM_h ----
    if (t < 256) {
        const float4 fv = *(const float4*)(frame + (size_t)b * 1024 + t * 4);
        *(float4*)(out + (size_t)b * 1536 + 512 + t * 4) = fv;
    }
}

extern "C" void kernel_launch(void* const* d_in, const int* in_sizes, int n_in,
                              void* d_out, int out_size, void* d_ws, size_t ws_size,
                              hipStream_t stream) {
    const float* query = (const float*)d_in[0];
    const float* keys  = (const float*)d_in[1];
    const float* frame = (const float*)d_in[2];
    const int*   mask  = (const int*)d_in[3];
    const float* W1    = (const float*)d_in[4];
    const float* W2    = (const float*)d_in[5];
    float* out = (float*)d_out;

    // ws: [0,64K) w1kt bf16 [64][512]; [64K,128K) proj f32 [256][64]
    bf16* w1kt  = (bf16*)d_ws;
    float* proj = (float*)((char*)d_ws + (64 << 10));

    hipFuncSetAttribute((const void*)attn_kernel,
                        hipFuncAttributeMaxDynamicSharedMemorySize, SMEM_BYTES);

    prep_kernel<<<72, 512, 0, stream>>>(W1, query, frame, w1kt, proj);
    attn_kernel<<<256, 512, SMEM_BYTES, stream>>>(keys, frame, mask, W2,
                                                  w1kt, proj, out);
}

// Round 8
// 123.058 us; speedup vs baseline: 1.1431x; 1.0044x over previous
//
#include <hip/hip_runtime.h>
#include <hip/hip_bf16.h>
#include <cstdint>
#include <math.h>

// Shapes: B=256, P=128, K=512, HE=1024, HF=512 (2HF=1024), D=2560, HID=64
// Outputs: embeddings (256,1,1536) then weights (256,128), fp32, flat-concat.
//
// R15: DIAGNOSTIC REVERT. R13/R14 (1024-thr split-K attn) killed the MI355X
//   container twice; audit found no OOB/hang, so either the 1024-thr combo
//   is the poison (H1) or infra is broken (H2). This round: byte-level
//   revert to the PASSING R12 structure with ONE safe delta — context
//   prefetch hoisted above softmax (loads fly during softmax/barrier-wait
//   instead of serial after). Pass => H1 (avoid 1024-thr); fail => H2.
// Ledger (kernels+gaps µs): R7 45 | R10 59 | R11 48.8 | R12 40.6 (passed,
//   123.6 total) | R13/R14 1024-thr: container died x2.
//   Floors: keys 64 MB HBM ~10.7, tail ~3, prep ~3.
// Fixed harness overhead: ~82 µs of 256 MiB workspace-poison fills per
//   iteration (2 x ~41 µs fillBufferAligned) — not addressable from here.

typedef __bf16 bf16;
typedef __attribute__((ext_vector_type(8))) __bf16 bf16x8;
typedef __attribute__((ext_vector_type(4))) float f32x4;

#define NB 256
#define NP 128
#define NK 512
#define SMEM_BYTES (65536 + 256 * 4)   // w1kt swizzled + scores[128] + wts[128]

// ---------------- prep: w1kt repack + fp32 proj GEMV ----------------
// blocks 0..7  : w1kt[h][k] = bf16(W1[k*64+h]), k-rows [64j, 64j+64)
// blocks 8..71 : proj[b][h] = sum_d qf[b][d]*W1[512+d][h], 4 batches/block,
//                8 waves, wave w covers d-chunk [256w, 256w+256)
__global__ __launch_bounds__(512) void prep_kernel(
    const float* __restrict__ W1, const float* __restrict__ query,
    const float* __restrict__ frame, bf16* __restrict__ w1kt,
    float* __restrict__ proj)
{
    __shared__ float s[64][65];       // repack staging (16.6 KB)
    __shared__ float sq[4][2048];     // qf for 4 batches (32 KB)
    __shared__ float red[8][4][64];   // cross-wave reduce (8 KB)
    const int blk = blockIdx.x;
    const int t = threadIdx.x;
    if (blk < 8) {
        const int k0 = blk * 64;
#pragma unroll
        for (int i = 0; i < 8; i++) {
            const int idx = t + 512 * i;
            const int k = idx >> 6, h = idx & 63;
            s[k][h] = W1[(size_t)(k0 + k) * 64 + h];
        }
        __syncthreads();
#pragma unroll
        for (int i = 0; i < 8; i++) {
            const int idx = t + 512 * i;
            const int h = idx >> 6, kk = idx & 63;
            w1kt[(size_t)h * 512 + k0 + kk] = (bf16)s[kk][h];
        }
    } else {
        const int b0 = (blk - 8) * 4;
        // stage qf = concat(query[b], frame[b]): 4 float4 / thread, coalesced
#pragma unroll
        for (int i = 0; i < 4; i++) {
            const int flat = (t + 512 * i) * 4;   // float index 0..8191
            const int bl = flat >> 11;            // local batch 0..3
            const int d  = flat & 2047;
            const float* src = (d < 1024)
                ? (query + (size_t)(b0 + bl) * 1024 + d)
                : (frame + (size_t)(b0 + bl) * 1024 + (d - 1024));
            *(float4*)&sq[bl][d] = *(const float4*)src;
        }
        __syncthreads();

        const int w = t >> 6;        // wave's d-chunk: [256w, 256w+256)
        const int h = t & 63;
        const float* w1c = W1 + (size_t)(512 + w * 256) * 64 + h;  // coalesced over h
        float wreg[4][16];           // depth-4 prefetch: 48 loads in flight
#pragma unroll
        for (int bu = 0; bu < 3; bu++)
#pragma unroll
            for (int u = 0; u < 16; u++)
                wreg[bu][u] = w1c[(size_t)(bu * 16 + u) * 64];

        float acc[4] = {0.f, 0.f, 0.f, 0.f};
#pragma unroll
        for (int rr = 0; rr < 16; rr++) {     // full unroll -> static indices
            const int cur = rr & 3;
            if (rr < 13) {
#pragma unroll
                for (int u = 0; u < 16; u++)
                    wreg[(rr + 3) & 3][u] = w1c[(size_t)((rr + 3) * 16 + u) * 64];
            }
#pragma unroll
            for (int u4 = 0; u4 < 4; u4++) {
                float4 qv[4];                 // LDS broadcast reads
#pragma unroll
                for (int j = 0; j < 4; j++)
                    qv[j] = *(const float4*)&sq[j][w * 256 + rr * 16 + u4 * 4];
#pragma unroll
                for (int uu = 0; uu < 4; uu++) {
                    const float wv = wreg[cur][u4 * 4 + uu];
                    acc[0] += (&qv[0].x)[uu] * wv;
                    acc[1] += (&qv[1].x)[uu] * wv;
                    acc[2] += (&qv[2].x)[uu] * wv;
                    acc[3] += (&qv[3].x)[uu] * wv;
                }
            }
        }
#pragma unroll
        for (int j = 0; j < 4; j++) red[w][j][h] = acc[j];
        __syncthreads();
        if (t < 256) {
            const int j2 = t >> 6, hh = t & 63;
            float sum = 0.f;
#pragma unroll
            for (int ww = 0; ww < 8; ww++) sum += red[ww][j2][hh];
            proj[(size_t)(b0 + j2) * 64 + hh] = sum;
        }
    }
}

// ---------------- attn: fused scores+softmax+context, 1 block/batch ----------------
// 512 thr = 8 waves; wave w owns p-rows [16w, 16w+16), full K=512.
// LDS: 64 KB swizzled w1kt + scores[128] + wts[128].
__global__ __launch_bounds__(512) void attn_kernel(
    const float* __restrict__ keys, const float* __restrict__ frame,
    const int* __restrict__ mask, const float* __restrict__ W2,
    const bf16* __restrict__ w1kt, const float* __restrict__ proj,
    float* __restrict__ out)
{
    extern __shared__ char smem[];
    char* sB      = smem;                        // 64 KB swizzled w1kt
    float* scores = (float*)(smem + 65536);      // [128]
    float* wts    = scores + 128;                // [128]

    const int b = blockIdx.x;
    const int t = threadIdx.x;
    const int w = t >> 6;
    const int lane = t & 63;
    const int m = lane & 15;
    const int q = lane >> 4;
    const int p0 = w * 16;
    const int xorv = (m & 7) << 4;               // read-side swizzle (bits 4-6)

    const float* arow = keys + (size_t)b * (NP * NK) + (size_t)(p0 + m) * NK + q * 8;

    // A prologue: distance-6 prefetch (12 loads) issued before staging
    float4 Aa[8], Ab[8];
#pragma unroll
    for (int i = 0; i < 6; i++) {
        Aa[i] = *(const float4*)(arow + i * 32);
        Ab[i] = *(const float4*)(arow + i * 32 + 4);
    }

    // stage w1kt -> LDS, swizzled: lds[o ^ ((row&7)<<4)] = w1kt_bytes[o]
    {
        const char* wsrc = (const char*)w1kt;
#pragma unroll
        for (int i = 0; i < 8; i++) {
            const int o = i * 8192 + t * 16;
            const int row = o >> 10;             // 1024 B per h-row
            *(bf16x8*)(sB + (o ^ ((row & 7) << 4))) = *(const bf16x8*)(wsrc + o);
        }
    }

    float pv[4], wv[4];
#pragma unroll
    for (int nt = 0; nt < 4; nt++) {
        pv[nt] = proj[b * 64 + nt * 16 + m];
        wv[nt] = W2[nt * 16 + m];
    }
    __syncthreads();   // one-time full drain; steady-state loop has no barrier

    f32x4 acc[4];
#pragma unroll
    for (int nt = 0; nt < 4; nt++) acc[nt] = (f32x4){0.f, 0.f, 0.f, 0.f};

    // B fragment addr: nt*16384 + m*1024 + ((kk*64 | q*16) ^ xorv)
    bf16x8 Bp[2][4];
#pragma unroll
    for (int nt = 0; nt < 4; nt++)
        Bp[0][nt] = *(const bf16x8*)(sB + nt * 16384 + m * 1024 + ((q * 16) ^ xorv));

#pragma unroll
    for (int kk = 0; kk < 16; kk++) {            // full unroll -> static indices
        const int cur = kk & 7;
        const int bc = kk & 1;
        if (kk < 10) {                           // A: distance-6, vmcnt-only queue
            Aa[(kk + 6) & 7] = *(const float4*)(arow + (kk + 6) * 32);
            Ab[(kk + 6) & 7] = *(const float4*)(arow + (kk + 6) * 32 + 4);
        }
        if (kk < 15) {                           // B: depth-1-ahead via lgkmcnt
#pragma unroll
            for (int nt = 0; nt < 4; nt++)
                Bp[bc ^ 1][nt] = *(const bf16x8*)(sB + nt * 16384 + m * 1024
                                  + ((((kk + 1) * 64) | (q * 16)) ^ xorv));
        }
        bf16x8 Af;
        Af[0] = (bf16)Aa[cur].x; Af[1] = (bf16)Aa[cur].y;
        Af[2] = (bf16)Aa[cur].z; Af[3] = (bf16)Aa[cur].w;
        Af[4] = (bf16)Ab[cur].x; Af[5] = (bf16)Ab[cur].y;
        Af[6] = (bf16)Ab[cur].z; Af[7] = (bf16)Ab[cur].w;
#pragma unroll
        for (int nt = 0; nt < 4; nt++)
            acc[nt] = __builtin_amdgcn_mfma_f32_16x16x32_bf16(Af, Bp[bc][nt], acc[nt], 0, 0, 0);
    }

    // fold 64 h-columns: relu(+proj) * w2, reduce over the 16 h-lanes
    float pr[4] = {0.f, 0.f, 0.f, 0.f};
#pragma unroll
    for (int nt = 0; nt < 4; nt++)
#pragma unroll
        for (int r = 0; r < 4; r++)
            pr[r] += fmaxf(acc[nt][r] + pv[nt], 0.f) * wv[nt];

#pragma unroll
    for (int off = 1; off < 16; off <<= 1)
#pragma unroll
        for (int r = 0; r < 4; r++)
            pr[r] += __shfl_xor(pr[r], off);

    if (m == 0) {
#pragma unroll
        for (int r = 0; r < 4; r++) scores[p0 + q * 4 + r] = pr[r];
    }
    __syncthreads();

    // ---- context prefetch HOISTED above softmax (R15 delta): loads fly
    //      during softmax (wave 0) / barrier-wait (waves 1-15) ----
    const float* kc = keys + (size_t)b * (NP * NK) + t;
    float kreg[2][16];
#pragma unroll
    for (int i = 0; i < 16; i++) kreg[0][i] = kc[(size_t)i * NK];

    // ---- masked softmax over 128 scores (first 64 lanes), write weights ----
    if (t < 64) {
        const int pa = t, pb = t + 64;
        float s0 = (mask[b * 128 + pa] == 0) ? -INFINITY : scores[pa];
        float s1 = (mask[b * 128 + pb] == 0) ? -INFINITY : scores[pb];
        float mx = fmaxf(s0, s1);
#pragma unroll
        for (int off = 32; off; off >>= 1) mx = fmaxf(mx, __shfl_xor(mx, off));
        float e0 = __expf(s0 - mx), e1 = __expf(s1 - mx);
        float sum = e0 + e1;
#pragma unroll
        for (int off = 32; off; off >>= 1) sum += __shfl_xor(sum, off);
        const float inv = 1.0f / sum;
        e0 *= inv; e1 *= inv;
        wts[pa] = e0; wts[pb] = e1;
        float* wout = out + (size_t)NB * 1536;
        wout[b * 128 + pa] = e0;
        wout[b * 128 + pb] = e1;
    }
    __syncthreads();

    // ---- context: thread t owns col t; keys[b] is L2/L3-hot (just streamed) ----
    {
        float acc2 = 0.f;
#pragma unroll
        for (int c8 = 0; c8 < 8; c8++) {         // full unroll -> static indices
            const int cu2 = c8 & 1;
            if (c8 < 7) {
#pragma unroll
                for (int i = 0; i < 16; i++)
                    kreg[cu2 ^ 1][i] = kc[(size_t)((c8 + 1) * 16 + i) * NK];
            }
#pragma unroll
            for (int i = 0; i < 16; i++)
                acc2 += wts[c8 * 16 + i] * kreg[cu2][i];
        }
        out[(size_t)b * 1536 + t] = acc2;
    }
    // ---- frame passthrough: embeddings[:, 512:1536] = frameLSTM_h ----
    if (t < 256) {
        const float4 fv = *(const float4*)(frame + (size_t)b * 1024 + t * 4);
        *(float4*)(out + (size_t)b * 1536 + 512 + t * 4) = fv;
    }
}

extern "C" void kernel_launch(void* const* d_in, const int* in_sizes, int n_in,
                              void* d_out, int out_size, void* d_ws, size_t ws_size,
                              hipStream_t stream) {
    const float* query = (const float*)d_in[0];
    const float* keys  = (const float*)d_in[1];
    const float* frame = (const float*)d_in[2];
    const int*   mask  = (const int*)d_in[3];
    const float* W1    = (const float*)d_in[4];
    const float* W2    = (const float*)d_in[5];
    float* out = (float*)d_out;

    // ws: [0,64K) w1kt bf16 [64][512]; [64K,128K) proj f32 [256][64]
    bf16* w1kt  = (bf16*)d_ws;
    float* proj = (float*)((char*)d_ws + (64 << 10));

    hipFuncSetAttribute((const void*)attn_kernel,
                        hipFuncAttributeMaxDynamicSharedMemorySize, SMEM_BYTES);

    prep_kernel<<<72, 512, 0, stream>>>(W1, query, frame, w1kt, proj);
    attn_kernel<<<256, 512, SMEM_BYTES, stream>>>(keys, frame, mask, W2,
                                                  w1kt, proj, out);
}

// Round 9
// 119.206 us; speedup vs baseline: 1.1800x; 1.0323x over previous
//
#include <hip/hip_runtime.h>
#include <hip/hip_bf16.h>
#include <cstdint>
#include <math.h>

// Shapes: B=256, P=128, K=512, HE=1024, HF=512 (2HF=1024), D=2560, HID=64
// Outputs: embeddings (256,1,1536) then weights (256,128), fp32, flat-concat.
//
// R16: SINGLE kernel, zero workspace. R15 confirmed 1024-thr kills the
//   container (avoid); 512-thr attn is <40 us but prep (64-blk GEMV @ 25%
//   CU occupancy) + launch gap hide inside the 41.7 us budget invisibly.
//   Now each block (1/batch, 512 thr): [1] qf->LDS + in-block W1k repack
//   (f32 coalesced read, bf16 cvt, swizzled ds_write_b128; W1 is
//   L3-broadcast) [2] in-block proj GEMV (8 waves x 256 d, ring-4x8)
//   [3] R15's MFMA scores loop + fold + softmax + hoisted-ctx + passthru.
//   No prep kernel, no w1kt/proj workspace round-trip, no launch gap.
// Ledger (kernels+gaps µs): R7 45 | R10 59 | R11 48.8 | R12 40.6 | R15 41.7.
//   Known: keys are L3-resident across iters (R0: FETCH 35.8 MB < 64 MB) ->
//   latency-bound, not BW. Compiler sinks load-rings under pressure (R7).
// Fixed harness overhead: ~81 µs of 256 MiB workspace-poison fills per
//   iteration (2 x ~40.5 µs fillBufferAligned) — not addressable from here.

typedef __bf16 bf16;
typedef __attribute__((ext_vector_type(8))) __bf16 bf16x8;
typedef __attribute__((ext_vector_type(4))) float f32x4;

#define NB 256
#define NP 128
#define NK 512
// LDS: sB 64K + sq 8K + red 2K + scores 512B + wts 512B
#define SMEM_BYTES (65536 + 8192 + 2048 + 512 + 512)   // 76800

__global__ __launch_bounds__(512) void fused_kernel(
    const float* __restrict__ keys, const float* __restrict__ query,
    const float* __restrict__ frame, const int* __restrict__ mask,
    const float* __restrict__ W1, const float* __restrict__ W2,
    float* __restrict__ out)
{
    extern __shared__ char smem[];
    char* sB      = smem;                          // 64 KB swizzled W1k bf16 [64][512]
    float* sq     = (float*)(smem + 65536);        // [2048] qf = query||frame
    float* red    = sq + 2048;                     // [8][64] proj wave partials
    float* scores = red + 512;                     // [128]
    float* wts    = scores + 128;                  // [128]

    const int b = blockIdx.x;
    const int t = threadIdx.x;
    const int w = t >> 6;              // wave 0..7
    const int lane = t & 63;
    const int m = lane & 15;
    const int q = lane >> 4;
    const int p0 = w * 16;             // wave's 16 p-rows
    const int xorv = (m & 7) << 4;     // read-side swizzle (bits 4-6)

    // ---- phase 1: qf stage (2048 f32, one float4/thread, coalesced) ----
    {
        const int d = t * 4;
        const float* src = (d < 1024) ? (query + (size_t)b * 1024 + d)
                                      : (frame + (size_t)b * 1024 + (d - 1024));
        *(float4*)&sq[d] = *(const float4*)src;
    }

    // ---- phase 2: in-block repack W1[0:512][64] -> sB[h][k] bf16 swizzled ----
    // thread owns (h, k-chunk of 8); the 8 f32 loads are coalesced per j
    // (lanes span h); one swizzled ds_write_b128 per chunk.
    {
#pragma unroll
        for (int i = 0; i < 8; i++) {
            const int id = t + 512 * i;         // 0..4095
            const int h = id & 63;
            const int kc = id >> 6;             // 0..63
            float v[8];
#pragma unroll
            for (int j = 0; j < 8; j++)
                v[j] = W1[(size_t)(kc * 8 + j) * 64 + h];
            bf16x8 bv;
#pragma unroll
            for (int j = 0; j < 8; j++) bv[j] = (bf16)v[j];
            *(bf16x8*)(sB + ((h * 1024 + kc * 16) ^ ((h & 7) << 4))) = bv;
        }
    }
    __syncthreads();

    // ---- phase 3: proj GEMV — wave w sums d in [256w,256w+256), h = lane ----
    {
        const float* w1p = W1 + (size_t)(512 + w * 256) * 64 + lane;
        float wr[4][8];                  // ring-4 x 8 d/round, distance-3
#pragma unroll
        for (int r0 = 0; r0 < 3; r0++)
#pragma unroll
            for (int j = 0; j < 8; j++)
                wr[r0][j] = w1p[(size_t)(r0 * 8 + j) * 64];
        float pacc = 0.f;
#pragma unroll 4
        for (int r = 0; r < 32; r++) {
            const int cur = r & 3;                  // static under unroll-4
            if (r < 29) {
#pragma unroll
                for (int j = 0; j < 8; j++)
                    wr[(r + 3) & 3][j] = w1p[(size_t)((r + 3) * 8 + j) * 64];
            }
            const float4 qa = *(const float4*)&sq[w * 256 + r * 8];
            const float4 qb = *(const float4*)&sq[w * 256 + r * 8 + 4];
            pacc += qa.x * wr[cur][0] + qa.y * wr[cur][1]
                  + qa.z * wr[cur][2] + qa.w * wr[cur][3]
                  + qb.x * wr[cur][4] + qb.y * wr[cur][5]
                  + qb.z * wr[cur][6] + qb.w * wr[cur][7];
        }
        red[w * 64 + lane] = pacc;
    }
    __syncthreads();

    // ---- phase 4: fold constants + A prologue (issued after proj so the
    //      in-loop vmcnt queue is A-only; one ~900cy stall at kk=0 max) ----
    float pv[4], wv[4];
#pragma unroll
    for (int nt = 0; nt < 4; nt++) {
        const int h = nt * 16 + m;
        float s = 0.f;
#pragma unroll
        for (int ww = 0; ww < 8; ww++) s += red[ww * 64 + h];
        pv[nt] = s;
        wv[nt] = W2[h];
    }

    const float* arow = keys + (size_t)b * (NP * NK) + (size_t)(p0 + m) * NK + q * 8;
    float4 Aa[8], Ab[8];
#pragma unroll
    for (int i = 0; i < 6; i++) {
        Aa[i] = *(const float4*)(arow + i * 32);
        Ab[i] = *(const float4*)(arow + i * 32 + 4);
    }

    // ---- phase 5: MFMA scores loop (R15 structure) ----
    f32x4 acc[4];
#pragma unroll
    for (int nt = 0; nt < 4; nt++) acc[nt] = (f32x4){0.f, 0.f, 0.f, 0.f};

    bf16x8 Bp[2][4];
#pragma unroll
    for (int nt = 0; nt < 4; nt++)
        Bp[0][nt] = *(const bf16x8*)(sB + nt * 16384 + m * 1024 + ((q * 16) ^ xorv));

#pragma unroll
    for (int kk = 0; kk < 16; kk++) {            // full unroll -> static indices
        const int cur = kk & 7;
        const int bc = kk & 1;
        if (kk < 10) {                           // A: distance-6, vmcnt-only queue
            Aa[(kk + 6) & 7] = *(const float4*)(arow + (kk + 6) * 32);
            Ab[(kk + 6) & 7] = *(const float4*)(arow + (kk + 6) * 32 + 4);
        }
        if (kk < 15) {                           // B: depth-1-ahead via lgkmcnt
#pragma unroll
            for (int nt = 0; nt < 4; nt++)
                Bp[bc ^ 1][nt] = *(const bf16x8*)(sB + nt * 16384 + m * 1024
                                  + ((((kk + 1) * 64) | (q * 16)) ^ xorv));
        }
        bf16x8 Af;
        Af[0] = (bf16)Aa[cur].x; Af[1] = (bf16)Aa[cur].y;
        Af[2] = (bf16)Aa[cur].z; Af[3] = (bf16)Aa[cur].w;
        Af[4] = (bf16)Ab[cur].x; Af[5] = (bf16)Ab[cur].y;
        Af[6] = (bf16)Ab[cur].z; Af[7] = (bf16)Ab[cur].w;
#pragma unroll
        for (int nt = 0; nt < 4; nt++)
            acc[nt] = __builtin_amdgcn_mfma_f32_16x16x32_bf16(Af, Bp[bc][nt], acc[nt], 0, 0, 0);
    }

    // fold 64 h-columns: relu(+proj) * w2, reduce over the 16 h-lanes
    float pr[4] = {0.f, 0.f, 0.f, 0.f};
#pragma unroll
    for (int nt = 0; nt < 4; nt++)
#pragma unroll
        for (int r = 0; r < 4; r++)
            pr[r] += fmaxf(acc[nt][r] + pv[nt], 0.f) * wv[nt];

#pragma unroll
    for (int off = 1; off < 16; off <<= 1)
#pragma unroll
        for (int r = 0; r < 4; r++)
            pr[r] += __shfl_xor(pr[r], off);

    if (m == 0) {
#pragma unroll
        for (int r = 0; r < 4; r++) scores[p0 + q * 4 + r] = pr[r];
    }
    __syncthreads();

    // ---- context prefetch hoisted above softmax (R15 delta) ----
    const float* kc = keys + (size_t)b * (NP * NK) + t;
    float kreg[2][16];
#pragma unroll
    for (int i = 0; i < 16; i++) kreg[0][i] = kc[(size_t)i * NK];

    // ---- masked softmax over 128 scores (first 64 lanes), write weights ----
    if (t < 64) {
        const int pa = t, pb = t + 64;
        float s0 = (mask[b * 128 + pa] == 0) ? -INFINITY : scores[pa];
        float s1 = (mask[b * 128 + pb] == 0) ? -INFINITY : scores[pb];
        float mx = fmaxf(s0, s1);
#pragma unroll
        for (int off = 32; off; off >>= 1) mx = fmaxf(mx, __shfl_xor(mx, off));
        float e0 = __expf(s0 - mx), e1 = __expf(s1 - mx);
        float sum = e0 + e1;
#pragma unroll
        for (int off = 32; off; off >>= 1) sum += __shfl_xor(sum, off);
        const float inv = 1.0f / sum;
        e0 *= inv; e1 *= inv;
        wts[pa] = e0; wts[pb] = e1;
        float* wout = out + (size_t)NB * 1536;
        wout[b * 128 + pa] = e0;
        wout[b * 128 + pb] = e1;
    }
    __syncthreads();

    // ---- context: thread t owns col t; keys[b] L2/L3-hot (just streamed) ----
    {
        float acc2 = 0.f;
#pragma unroll
        for (int c8 = 0; c8 < 8; c8++) {         // full unroll -> static indices
            const int cu2 = c8 & 1;
            if (c8 < 7) {
#pragma unroll
                for (int i = 0; i < 16; i++)
                    kreg[cu2 ^ 1][i] = kc[(size_t)((c8 + 1) * 16 + i) * NK];
            }
#pragma unroll
            for (int i = 0; i < 16; i++)
                acc2 += wts[c8 * 16 + i] * kreg[cu2][i];
        }
        out[(size_t)b * 1536 + t] = acc2;
    }
    // ---- frame passthrough: embeddings[:, 512:1536] = frameLSTM_h ----
    if (t < 256) {
        const float4 fv = *(const float4*)(frame + (size_t)b * 1024 + t * 4);
        *(float4*)(out + (size_t)b * 1536 + 512 + t * 4) = fv;
    }
}

extern "C" void kernel_launch(void* const* d_in, const int* in_sizes, int n_in,
                              void* d_out, int out_size, void* d_ws, size_t ws_size,
                              hipStream_t stream) {
    const float* query = (const float*)d_in[0];
    const float* keys  = (const float*)d_in[1];
    const float* frame = (const float*)d_in[2];
    const int*   mask  = (const int*)d_in[3];
    const float* W1    = (const float*)d_in[4];
    const float* W2    = (const float*)d_in[5];
    float* out = (float*)d_out;

    hipFuncSetAttribute((const void*)fused_kernel,
                        hipFuncAttributeMaxDynamicSharedMemorySize, SMEM_BYTES);

    fused_kernel<<<256, 512, SMEM_BYTES, stream>>>(keys, query, frame, mask,
                                                   W1, W2, out);
}

// Round 10
// 118.459 us; speedup vs baseline: 1.1875x; 1.0063x over previous
//
#include <hip/hip_runtime.h>
#include <hip/hip_bf16.h>
#include <cstdint>
#include <math.h>

// Shapes: B=256, P=128, K=512, HE=1024, HF=512 (2HF=1024), D=2560, HID=64
// Outputs: embeddings (256,1,1536) then weights (256,128), fp32, flat-concat.
//
// R17: R16's counters: fused 42.5 us, MfmaUtil 1.7, VALUBusy 10.6, HBM 20%
//   -> 85% stall. VGPR_Count=48 PROVES the compiler deleted every prefetch
//   ring (Aa[8]/Ab[8] alone = 64 VGPRs): with __launch_bounds__(512) and no
//   min-waves, the backend schedules for max occupancy and sinks loads to
//   consumers (grid 256 = 1 block/CU caps occupancy anyway, so this buys
//   nothing). Fixes:
//   [1] __launch_bounds__(512, 2): true occupancy declared; VGPR cap 256;
//       scheduler licensed to keep rings. Diagnostic: VGPR>=120 next round.
//   [2] G13: proj GEMV was 256 SCALAR stride-256B loads/thread -> float4-
//       over-h (thread=(d-slice s, h-quad j): 64 float4), shuffle+LDS reduce.
//   [3] G13: context was 128 scalar stride-2KB loads/thread -> thread=
//       (col-quad, p-group): 32 float4 + LDS combine; batch-0 hoisted above
//       softmax (R15 delta kept).
// Ledger (kernels+gaps µs): R7 45 | R11 48.8 | R12 40.6 | R15 41.7 |
//   R16 fused 42.5 (VISIBLE: latency-bound, rings deleted).
// Fixed harness overhead: ~81 µs of 256 MiB workspace-poison fills/iter.

typedef __bf16 bf16;
typedef __attribute__((ext_vector_type(8))) __bf16 bf16x8;
typedef __attribute__((ext_vector_type(4))) float f32x4;

#define NB 256
#define NP 128
#define NK 512
// LDS: sB 64K + sq 8K + aux 8K (proj-red 2K / ctx-cred 8K, time-disjoint)
//      + scores 512B + wts 512B = 82944
#define SMEM_BYTES (65536 + 8192 + 8192 + 512 + 512)

__global__ __launch_bounds__(512, 2) void fused_kernel(
    const float* __restrict__ keys, const float* __restrict__ query,
    const float* __restrict__ frame, const int* __restrict__ mask,
    const float* __restrict__ W1, const float* __restrict__ W2,
    float* __restrict__ out)
{
    extern __shared__ char smem[];
    char* sB      = smem;                          // 64 KB swizzled W1k bf16 [64][512]
    float* sq     = (float*)(smem + 65536);        // [2048] qf = query||frame
    float* aux    = sq + 2048;                     // [2048] red[8][64] / cred[4][512]
    float* scores = aux + 2048;                    // [128]
    float* wts    = scores + 128;                  // [128]

    const int b = blockIdx.x;
    const int t = threadIdx.x;
    const int w = t >> 6;              // wave 0..7
    const int lane = t & 63;
    const int m = lane & 15;
    const int q = lane >> 4;
    const int p0 = w * 16;             // wave's 16 p-rows (scores phase)
    const int xorv = (m & 7) << 4;     // read-side swizzle (bits 4-6)

    // ---- phase 1: qf stage (2048 f32, one float4/thread, coalesced) ----
    {
        const int d = t * 4;
        const float* src = (d < 1024) ? (query + (size_t)b * 1024 + d)
                                      : (frame + (size_t)b * 1024 + (d - 1024));
        *(float4*)&sq[d] = *(const float4*)src;
    }

    // ---- phase 2: in-block repack W1[0:512][64] -> sB[h][k] bf16 swizzled ----
    {
#pragma unroll
        for (int i = 0; i < 8; i++) {
            const int id = t + 512 * i;         // 0..4095
            const int h = id & 63;
            const int kc = id >> 6;             // 0..63
            float v[8];
#pragma unroll
            for (int j = 0; j < 8; j++)
                v[j] = W1[(size_t)(kc * 8 + j) * 64 + h];
            bf16x8 bv;
#pragma unroll
            for (int j = 0; j < 8; j++) bv[j] = (bf16)v[j];
            *(bf16x8*)(sB + ((h * 1024 + kc * 16) ^ ((h & 7) << 4))) = bv;
        }
    }
    __syncthreads();

    // ---- phase 3: proj GEMV, float4-over-h. thread = (s = d-slice, j = h-quad):
    //      acc4[h=4j..4j+3] += sum_{d in slice s} sq[d] * W1[512+d][4j..4j+4) ----
    {
        const int s = t >> 4;          // 0..31: d-rows [64s, 64s+64)
        const int j = t & 15;          // h-quad
        const float4* w1f4 = (const float4*)W1;
        float4 pa = {0.f, 0.f, 0.f, 0.f};
#pragma unroll
        for (int bt = 0; bt < 8; bt++) {
            float4 vv[8];
#pragma unroll
            for (int i = 0; i < 8; i++)
                vv[i] = w1f4[(size_t)(512 + s * 64 + bt * 8 + i) * 16 + j];
#pragma unroll
            for (int i = 0; i < 8; i++) {
                const float qv = sq[s * 64 + bt * 8 + i];
                pa.x += qv * vv[i].x; pa.y += qv * vv[i].y;
                pa.z += qv * vv[i].z; pa.w += qv * vv[i].w;
            }
        }
        // in-wave reduce over the wave's 4 d-slices (lane>>4), then LDS
        pa.x += __shfl_xor(pa.x, 16); pa.y += __shfl_xor(pa.y, 16);
        pa.z += __shfl_xor(pa.z, 16); pa.w += __shfl_xor(pa.w, 16);
        pa.x += __shfl_xor(pa.x, 32); pa.y += __shfl_xor(pa.y, 32);
        pa.z += __shfl_xor(pa.z, 32); pa.w += __shfl_xor(pa.w, 32);
        if (lane < 16)
            *(float4*)&aux[w * 64 + lane * 4] = pa;   // red[w][h=4j..4j+3]
    }
    __syncthreads();

    // ---- phase 4: fold constants + A prologue (A-only vmcnt queue) ----
    float pv[4], wv[4];
#pragma unroll
    for (int nt = 0; nt < 4; nt++) {
        const int h = nt * 16 + m;
        float sacc = 0.f;
#pragma unroll
        for (int ww = 0; ww < 8; ww++) sacc += aux[ww * 64 + h];
        pv[nt] = sacc;
        wv[nt] = W2[h];
    }

    const float* arow = keys + (size_t)b * (NP * NK) + (size_t)(p0 + m) * NK + q * 8;
    float4 Aa[8], Ab[8];
#pragma unroll
    for (int i = 0; i < 6; i++) {
        Aa[i] = *(const float4*)(arow + i * 32);
        Ab[i] = *(const float4*)(arow + i * 32 + 4);
    }

    // ---- phase 5: MFMA scores loop ----
    f32x4 acc[4];
#pragma unroll
    for (int nt = 0; nt < 4; nt++) acc[nt] = (f32x4){0.f, 0.f, 0.f, 0.f};

    bf16x8 Bp[2][4];
#pragma unroll
    for (int nt = 0; nt < 4; nt++)
        Bp[0][nt] = *(const bf16x8*)(sB + nt * 16384 + m * 1024 + ((q * 16) ^ xorv));

#pragma unroll
    for (int kk = 0; kk < 16; kk++) {            // full unroll -> static indices
        const int cur = kk & 7;
        const int bc = kk & 1;
        if (kk < 10) {                           // A: distance-6, vmcnt-only queue
            Aa[(kk + 6) & 7] = *(const float4*)(arow + (kk + 6) * 32);
            Ab[(kk + 6) & 7] = *(const float4*)(arow + (kk + 6) * 32 + 4);
        }
        if (kk < 15) {                           // B: depth-1-ahead via lgkmcnt
#pragma unroll
            for (int nt = 0; nt < 4; nt++)
                Bp[bc ^ 1][nt] = *(const bf16x8*)(sB + nt * 16384 + m * 1024
                                  + ((((kk + 1) * 64) | (q * 16)) ^ xorv));
        }
        bf16x8 Af;
        Af[0] = (bf16)Aa[cur].x; Af[1] = (bf16)Aa[cur].y;
        Af[2] = (bf16)Aa[cur].z; Af[3] = (bf16)Aa[cur].w;
        Af[4] = (bf16)Ab[cur].x; Af[5] = (bf16)Ab[cur].y;
        Af[6] = (bf16)Ab[cur].z; Af[7] = (bf16)Ab[cur].w;
#pragma unroll
        for (int nt = 0; nt < 4; nt++)
            acc[nt] = __builtin_amdgcn_mfma_f32_16x16x32_bf16(Af, Bp[bc][nt], acc[nt], 0, 0, 0);
    }

    // fold 64 h-columns: relu(+proj) * w2, reduce over the 16 h-lanes
    float pr[4] = {0.f, 0.f, 0.f, 0.f};
#pragma unroll
    for (int nt = 0; nt < 4; nt++)
#pragma unroll
        for (int r = 0; r < 4; r++)
            pr[r] += fmaxf(acc[nt][r] + pv[nt], 0.f) * wv[nt];

#pragma unroll
    for (int off = 1; off < 16; off <<= 1)
#pragma unroll
        for (int r = 0; r < 4; r++)
            pr[r] += __shfl_xor(pr[r], off);

    if (m == 0) {
#pragma unroll
        for (int r = 0; r < 4; r++) scores[p0 + q * 4 + r] = pr[r];
    }
    __syncthreads();

    // ---- ctx batch-0 prefetch hoisted above softmax (R15 delta) ----
    // thread = (cq = col-quad 0..127, pg = p-group 0..3 of 32 rows)
    const int cq = t & 127;
    const int pg = t >> 7;
    const float4* kp4 = (const float4*)(keys + (size_t)b * (NP * NK));
    float4 kv0[8];
#pragma unroll
    for (int i = 0; i < 8; i++)
        kv0[i] = kp4[(size_t)(pg * 32 + i) * 128 + cq];

    // ---- masked softmax over 128 scores (first 64 lanes), write weights ----
    if (t < 64) {
        const int pa = t, pb = t + 64;
        float s0 = (mask[b * 128 + pa] == 0) ? -INFINITY : scores[pa];
        float s1 = (mask[b * 128 + pb] == 0) ? -INFINITY : scores[pb];
        float mx = fmaxf(s0, s1);
#pragma unroll
        for (int off = 32; off; off >>= 1) mx = fmaxf(mx, __shfl_xor(mx, off));
        float e0 = __expf(s0 - mx), e1 = __expf(s1 - mx);
        float sum = e0 + e1;
#pragma unroll
        for (int off = 32; off; off >>= 1) sum += __shfl_xor(sum, off);
        const float inv = 1.0f / sum;
        e0 *= inv; e1 *= inv;
        wts[pa] = e0; wts[pb] = e1;
        float* wout = out + (size_t)NB * 1536;
        wout[b * 128 + pa] = e0;
        wout[b * 128 + pb] = e1;
    }
    __syncthreads();

    // ---- context: float4 cols, p-split x4, LDS combine ----
    {
        float4 ca = {0.f, 0.f, 0.f, 0.f};
#pragma unroll
        for (int i = 0; i < 8; i++) {
            const float wvv = wts[pg * 32 + i];
            ca.x += wvv * kv0[i].x; ca.y += wvv * kv0[i].y;
            ca.z += wvv * kv0[i].z; ca.w += wvv * kv0[i].w;
        }
#pragma unroll
        for (int bt = 1; bt < 4; bt++) {
            float4 kv[8];
#pragma unroll
            for (int i = 0; i < 8; i++)
                kv[i] = kp4[(size_t)(pg * 32 + bt * 8 + i) * 128 + cq];
#pragma unroll
            for (int i = 0; i < 8; i++) {
                const float wvv = wts[pg * 32 + bt * 8 + i];
                ca.x += wvv * kv[i].x; ca.y += wvv * kv[i].y;
                ca.z += wvv * kv[i].z; ca.w += wvv * kv[i].w;
            }
        }
        *(float4*)&aux[pg * 512 + cq * 4] = ca;   // cred[pg][col-quad]
    }
    __syncthreads();
    {
        const int c = t;
        if (c < 512)
            out[(size_t)b * 1536 + c] =
                aux[c] + aux[512 + c] + aux[1024 + c] + aux[1536 + c];
    }
    // ---- frame passthrough: embeddings[:, 512:1536] = frameLSTM_h ----
    if (t < 256) {
        const float4 fv = *(const float4*)(frame + (size_t)b * 1024 + t * 4);
        *(float4*)(out + (size_t)b * 1536 + 512 + t * 4) = fv;
    }
}

extern "C" void kernel_launch(void* const* d_in, const int* in_sizes, int n_in,
                              void* d_out, int out_size, void* d_ws, size_t ws_size,
                              hipStream_t stream) {
    const float* query = (const float*)d_in[0];
    const float* keys  = (const float*)d_in[1];
    const float* frame = (const float*)d_in[2];
    const int*   mask  = (const int*)d_in[3];
    const float* W1    = (const float*)d_in[4];
    const float* W2    = (const float*)d_in[5];
    float* out = (float*)d_out;

    hipFuncSetAttribute((const void*)fused_kernel,
                        hipFuncAttributeMaxDynamicSharedMemorySize, SMEM_BYTES);

    fused_kernel<<<256, 512, SMEM_BYTES, stream>>>(keys, query, frame, mask,
                                                   W1, W2, out);
}